// Round 2
// baseline (850.025 us; speedup 1.0000x reference)
//
#include <hip/hip_runtime.h>
#include <hip/hip_bf16.h>

// HeteroSAGE collapsed pipeline (all float32 I/O, bf16 MFMA internally):
//   out[i] = mean_cites(s_c[src]) + mean_writes(s_w[src]) + s_r[i] + C0
//   s_c = p1 . (W2l_cites@Wh), s_r = p1 . ((W2r_cites+W2r_writes)@Wh)
//   s_w = a1 . (W2l_writes@Wh)
//   p1  = relu(mean_c(Yp[:,0:32]) + mean_w(Ya[:,0:32]) + Yp[:,64:96] + b1c + b1w)
//   a1  = relu(mean_r(Yp[:,32:64]) + Ya[:,32:64] + b1rev)
//   Yp = x_paper @ [W1l_cites | W1l_rev | W1r_cites+W1r_writes]   (MFMA bf16)
//   Ya = x_author @ [W1l_writes | W1r_rev]

typedef __bf16 bf16x8 __attribute__((ext_vector_type(8)));
typedef float f32x4 __attribute__((ext_vector_type(4)));

// ---------------- prep: combined transposed weights (f32 -> bf16) + head vecs --
__global__ void prep_kernel(const float* W1l_c, const float* W1l_rev,
                            const float* W1r_c, const float* W1r_w,
                            const float* W1l_w, const float* W1r_rev,
                            const float* W2l_c, const float* W2l_w,
                            const float* W2r_c, const float* W2r_w,
                            const float* b2l_c, const float* b2l_w,
                            const float* Wh, const float* bh,
                            __bf16* Bp_t, __bf16* Ba_t, float* uvec) {
    int t = threadIdx.x;  // one block, 256 threads
    // Bp_t[n][k]  n<96, k<128  (B^T for MFMA: contiguous k per output col)
    for (int idx = t; idx < 96 * 128; idx += 256) {
        int n = idx >> 7, k = idx & 127;
        float v;
        if (n < 32)      v = W1l_c[k * 32 + n];
        else if (n < 64) v = W1l_rev[k * 32 + (n - 32)];
        else             v = W1r_c[k * 32 + (n - 64)] + W1r_w[k * 32 + (n - 64)];
        Bp_t[n * 128 + k] = (__bf16)v;
    }
    // Ba_t[n][k]  n<64, k<64
    for (int idx = t; idx < 64 * 64; idx += 256) {
        int n = idx >> 6, k = idx & 63;
        float v = (n < 32) ? W1l_w[k * 32 + n] : W1r_rev[k * 32 + (n - 32)];
        Ba_t[n * 64 + k] = (__bf16)v;
    }
    if (t < 32) {
        float uc = 0.f, uw = 0.f, ur = 0.f;
        for (int j = 0; j < 32; ++j) {
            float wh = Wh[j];
            uc += W2l_c[t * 32 + j] * wh;
            uw += W2l_w[t * 32 + j] * wh;
            ur += (W2r_c[t * 32 + j] + W2r_w[t * 32 + j]) * wh;
        }
        uvec[t] = uc; uvec[32 + t] = uw; uvec[64 + t] = ur;
        if (t == 0) {
            float c0 = bh[0];
            for (int j = 0; j < 32; ++j)
                c0 += (b2l_c[j] + b2l_w[j]) * Wh[j];
            uvec[96] = c0;
        }
    }
}

// ---------------- projection GEMM: Y[M,N](bf16) = X[M,K](f32) @ Bt^T -----------
// One wave per 16-row tile; B fragments held in VGPRs (no LDS).
// MFMA 16x16x32 bf16 layouts (HW-verified per guide §3):
//   A: lane holds A[m=lane&15][k=quad*8+j]   B: B[k=quad*8+j][n=lane&15]
//   C/D: col=lane&15, row=quad*4+reg
template <int K, int N>
__global__ __launch_bounds__(256) void proj_kernel(const float* __restrict__ X,
                                                   const __bf16* __restrict__ Bt,
                                                   __bf16* __restrict__ Y, int M) {
    constexpr int NT = N / 16, KT = K / 32;
    int lane = threadIdx.x & 63;
    int wave = (blockIdx.x * 256 + threadIdx.x) >> 6;
    int m0 = wave * 16;
    if (m0 + 16 > M) return;  // M is a multiple of 16 for this problem
    int lr = lane & 15;
    int quad = lane >> 4;

    bf16x8 bfrag[NT][KT];
#pragma unroll
    for (int ct = 0; ct < NT; ++ct)
#pragma unroll
        for (int ks = 0; ks < KT; ++ks)
            bfrag[ct][ks] = *(const bf16x8*)(Bt + (ct * 16 + lr) * K + ks * 32 + quad * 8);

    bf16x8 afrag[KT];
    const float* xrow = X + (size_t)(m0 + lr) * K + quad * 8;
#pragma unroll
    for (int ks = 0; ks < KT; ++ks) {
        f32x4 lo = *(const f32x4*)(xrow + ks * 32);
        f32x4 hi = *(const f32x4*)(xrow + ks * 32 + 4);
        bf16x8 a;
#pragma unroll
        for (int j = 0; j < 4; ++j) { a[j] = (__bf16)lo[j]; a[4 + j] = (__bf16)hi[j]; }
        afrag[ks] = a;
    }

#pragma unroll
    for (int ct = 0; ct < NT; ++ct) {
        f32x4 acc = {0.f, 0.f, 0.f, 0.f};
#pragma unroll
        for (int ks = 0; ks < KT; ++ks)
            acc = __builtin_amdgcn_mfma_f32_16x16x32_bf16(afrag[ks], bfrag[ct][ks], acc, 0, 0, 0);
        int rbase = m0 + quad * 4;
#pragma unroll
        for (int r = 0; r < 4; ++r)
            Y[(size_t)(rbase + r) * N + ct * 16 + lr] = (__bf16)acc[r];
    }
}

// ---------------- CSR build (3 relations share one counter/offset space) -------
// global dst index: cites dst -> [0,NP), writes dst -> NP+[0,NP), rev dst -> 2NP+[0,NA)
__global__ void hist_kernel(const int* __restrict__ eiC, const int* __restrict__ eiW,
                            const int* __restrict__ eiR, int* counts, int NP, int E) {
    int g = blockIdx.x * blockDim.x + threadIdx.x;
    if (g >= 3 * E) return;
    int idx;
    if (g < E)           idx = eiC[E + g];
    else if (g < 2 * E)  idx = NP + eiW[E + (g - E)];
    else                 idx = 2 * NP + eiR[E + (g - 2 * E)];
    atomicAdd(&counts[idx], 1);
}

__global__ void scan1_kernel(const int* __restrict__ counts, int* bsums, int M) {
    __shared__ int red[4];
    int b = blockIdx.x, t = threadIdx.x;
    int i0 = b * 1024 + t * 4;
    int s = 0;
    for (int j = 0; j < 4; ++j) { int i = i0 + j; if (i < M) s += counts[i]; }
    for (int m = 1; m < 64; m <<= 1) s += __shfl_xor(s, m, 64);
    if ((t & 63) == 0) red[t >> 6] = s;
    __syncthreads();
    if (t == 0) bsums[b] = red[0] + red[1] + red[2] + red[3];
}

__global__ void scan2_kernel(int* bsums, int nb) {  // nb <= 1024; one block of 512
    __shared__ int sh[1024];
    int t = threadIdx.x;
    for (int i = t; i < 1024; i += 512) sh[i] = (i < nb) ? bsums[i] : 0;
    __syncthreads();
    for (int d = 1; d < 1024; d <<= 1) {
        int v0 = sh[t] + ((t >= d) ? sh[t - d] : 0);
        int i1 = t + 512;
        int v1 = sh[i1] + ((i1 >= d) ? sh[i1 - d] : 0);
        __syncthreads();
        sh[t] = v0; sh[i1] = v1;
        __syncthreads();
    }
    for (int i = t; i < 1024; i += 512)
        if (i < nb) bsums[i] = i ? sh[i - 1] : 0;  // exclusive
}

__global__ void scan3_kernel(const int* __restrict__ counts, const int* __restrict__ bsums,
                             int* offsets, int* cursor, int M) {
    __shared__ int sh[256];
    int b = blockIdx.x, t = threadIdx.x;
    int i0 = b * 1024 + t * 4;
    int c[4]; int tot = 0;
    for (int j = 0; j < 4; ++j) { int i = i0 + j; c[j] = (i < M) ? counts[i] : 0; tot += c[j]; }
    sh[t] = tot;
    __syncthreads();
    for (int d = 1; d < 256; d <<= 1) {
        int v = sh[t] + ((t >= d) ? sh[t - d] : 0);
        __syncthreads();
        sh[t] = v;
        __syncthreads();
    }
    int excl = sh[t] - tot + bsums[b];
    for (int j = 0; j < 4; ++j) {
        int i = i0 + j;
        if (i < M) { offsets[i] = excl; cursor[i] = excl; }
        excl += c[j];
    }
}

__global__ void fill_kernel(const int* __restrict__ eiC, const int* __restrict__ eiW,
                            const int* __restrict__ eiR, int* cursor, int* csr,
                            int NP, int E) {
    int g = blockIdx.x * blockDim.x + threadIdx.x;
    if (g >= 3 * E) return;
    int idx, src;
    if (g < E)          { idx = eiC[E + g];                 src = eiC[g]; }
    else if (g < 2 * E) { int e = g - E;     idx = NP + eiW[E + e];     src = eiW[e]; }
    else                { int e = g - 2 * E; idx = 2 * NP + eiR[E + e]; src = eiR[e]; }
    int pos = atomicAdd(&cursor[idx], 1);
    csr[pos] = src;
}

// ---------------- layer-1 fused aggregation + layer-2 scalar projection -------
// 32 lanes per node (lane = channel); 8 nodes per 256-thread block.
__global__ __launch_bounds__(256) void paper_l1_kernel(
    const __bf16* __restrict__ Yp, const __bf16* __restrict__ Ya,
    const int* __restrict__ counts, const int* __restrict__ offsets,
    const int* __restrict__ csr, const float* __restrict__ b1l_c,
    const float* __restrict__ b1l_w, const float* __restrict__ uvec,
    float* __restrict__ s_c, float* __restrict__ s_r, int NP) {
    int grp = (blockIdx.x * blockDim.x + threadIdx.x) >> 5;
    int c = threadIdx.x & 31;
    if (grp >= NP) return;
    int i = grp;
    float acc = (float)Yp[(size_t)i * 96 + 64 + c] + b1l_c[c] + b1l_w[c];
    int cc = counts[i], o = offsets[i];
    float s = 0.f;
    for (int e = 0; e < cc; ++e) s += (float)Yp[(size_t)csr[o + e] * 96 + c];
    acc += s / (float)max(cc, 1);
    int cw = counts[NP + i], o2 = offsets[NP + i];
    float s2 = 0.f;
    for (int e = 0; e < cw; ++e) s2 += (float)Ya[(size_t)csr[o2 + e] * 64 + c];
    acc += s2 / (float)max(cw, 1);
    float p = fmaxf(acc, 0.f);
    float vc = p * uvec[c];
    float vr = p * uvec[64 + c];
    for (int m = 1; m < 32; m <<= 1) { vc += __shfl_xor(vc, m, 64); vr += __shfl_xor(vr, m, 64); }
    if (c == 0) { s_c[i] = vc; s_r[i] = vr; }
}

__global__ __launch_bounds__(256) void author_l1_kernel(
    const __bf16* __restrict__ Yp, const __bf16* __restrict__ Ya,
    const int* __restrict__ counts, const int* __restrict__ offsets,
    const int* __restrict__ csr, const float* __restrict__ b1l_rev,
    const float* __restrict__ uvec, float* __restrict__ s_w, int NP, int NA) {
    int grp = (blockIdx.x * blockDim.x + threadIdx.x) >> 5;
    int c = threadIdx.x & 31;
    if (grp >= NA) return;
    int j = grp;
    float acc = (float)Ya[(size_t)j * 64 + 32 + c] + b1l_rev[c];
    int cr = counts[2 * NP + j], o = offsets[2 * NP + j];
    float s = 0.f;
    for (int e = 0; e < cr; ++e) s += (float)Yp[(size_t)csr[o + e] * 96 + 32 + c];
    acc += s / (float)max(cr, 1);
    float p = fmaxf(acc, 0.f);
    float vw = p * uvec[32 + c];
    for (int m = 1; m < 32; m <<= 1) vw += __shfl_xor(vw, m, 64);
    if (c == 0) s_w[j] = vw;
}

// ---------------- final: scalar aggregation + write f32 output ----------------
__global__ void out_kernel(const float* __restrict__ s_c, const float* __restrict__ s_w,
                           const float* __restrict__ s_r, const int* __restrict__ counts,
                           const int* __restrict__ offsets, const int* __restrict__ csr,
                           const float* __restrict__ uvec, float* __restrict__ out, int NP) {
    int i = blockIdx.x * blockDim.x + threadIdx.x;
    if (i >= NP) return;
    int cc = counts[i], o = offsets[i];
    float s = 0.f;
    for (int e = 0; e < cc; ++e) s += s_c[csr[o + e]];
    int cw = counts[NP + i], o2 = offsets[NP + i];
    float s2 = 0.f;
    for (int e = 0; e < cw; ++e) s2 += s_w[csr[o2 + e]];
    out[i] = s / (float)max(cc, 1) + s2 / (float)max(cw, 1) + s_r[i] + uvec[96];
}

extern "C" void kernel_launch(void* const* d_in, const int* in_sizes, int n_in,
                              void* d_out, int out_size, void* d_ws, size_t ws_size,
                              hipStream_t stream) {
    const float* x_paper  = (const float*)d_in[0];
    const float* x_author = (const float*)d_in[1];
    const int* eiC = (const int*)d_in[2];
    const int* eiW = (const int*)d_in[3];
    const int* eiR = (const int*)d_in[4];
    const float* W1l_c  = (const float*)d_in[5];
    const float* b1l_c  = (const float*)d_in[6];
    const float* W1r_c  = (const float*)d_in[7];
    const float* W1l_w  = (const float*)d_in[8];
    const float* b1l_w  = (const float*)d_in[9];
    const float* W1r_w  = (const float*)d_in[10];
    const float* W1l_r  = (const float*)d_in[11];
    const float* b1l_r  = (const float*)d_in[12];
    const float* W1r_r  = (const float*)d_in[13];
    const float* W2l_c  = (const float*)d_in[14];
    const float* b2l_c  = (const float*)d_in[15];
    const float* W2r_c  = (const float*)d_in[16];
    const float* W2l_w  = (const float*)d_in[17];
    const float* b2l_w  = (const float*)d_in[18];
    const float* W2r_w  = (const float*)d_in[19];
    // d_in[20..22] = W2l_rev/b2l_rev/W2r_rev: unused (author output not consumed)
    const float* Wh = (const float*)d_in[23];
    const float* bh = (const float*)d_in[24];

    const int NP = in_sizes[0] / 128;
    const int NA = in_sizes[1] / 64;
    const int E  = in_sizes[2] / 2;
    const int M  = 2 * NP + NA;  // combined dst-counter space

    // ---- workspace carve (256B aligned) ----
    char* p = (char*)d_ws;
    auto alloc = [&](size_t bytes) -> void* {
        void* r = (void*)p;
        p += (bytes + 255) & ~(size_t)255;
        return r;
    };
    __bf16* Yp   = (__bf16*)alloc((size_t)NP * 96 * 2);
    __bf16* Ya   = (__bf16*)alloc((size_t)NA * 64 * 2);
    __bf16* Bp_t = (__bf16*)alloc(96 * 128 * 2);
    __bf16* Ba_t = (__bf16*)alloc(64 * 64 * 2);
    float* uvec  = (float*)alloc(128 * 4);
    float* s_c   = (float*)alloc((size_t)NP * 4);
    float* s_r   = (float*)alloc((size_t)NP * 4);
    float* s_w   = (float*)alloc((size_t)NA * 4);
    int* counts  = (int*)alloc((size_t)M * 4);
    int* offsets = (int*)alloc((size_t)M * 4);
    int* cursor  = (int*)alloc((size_t)M * 4);
    int* bsums   = (int*)alloc(1024 * 4);
    int* csr     = (int*)alloc((size_t)3 * E * 4);

    hipMemsetAsync(counts, 0, (size_t)M * 4, stream);

    prep_kernel<<<1, 256, 0, stream>>>(W1l_c, W1l_r, W1r_c, W1r_w, W1l_w, W1r_r,
                                       W2l_c, W2l_w, W2r_c, W2r_w, b2l_c, b2l_w,
                                       Wh, bh, Bp_t, Ba_t, uvec);

    proj_kernel<128, 96><<<(NP + 63) / 64, 256, 0, stream>>>(x_paper, Bp_t, Yp, NP);
    proj_kernel<64, 64><<<(NA + 63) / 64, 256, 0, stream>>>(x_author, Ba_t, Ya, NA);

    int e3blocks = (3 * E + 255) / 256;
    hist_kernel<<<e3blocks, 256, 0, stream>>>(eiC, eiW, eiR, counts, NP, E);
    int nb = (M + 1023) / 1024;
    scan1_kernel<<<nb, 256, 0, stream>>>(counts, bsums, M);
    scan2_kernel<<<1, 512, 0, stream>>>(bsums, nb);
    scan3_kernel<<<nb, 256, 0, stream>>>(counts, bsums, offsets, cursor, M);
    fill_kernel<<<e3blocks, 256, 0, stream>>>(eiC, eiW, eiR, cursor, csr, NP, E);

    paper_l1_kernel<<<(NP * 32 + 255) / 256, 256, 0, stream>>>(
        Yp, Ya, counts, offsets, csr, b1l_c, b1l_w, uvec, s_c, s_r, NP);
    author_l1_kernel<<<(NA * 32 + 255) / 256, 256, 0, stream>>>(
        Yp, Ya, counts, offsets, csr, b1l_r, uvec, s_w, NP, NA);
    out_kernel<<<(NP + 255) / 256, 256, 0, stream>>>(
        s_c, s_w, s_r, counts, offsets, csr, uvec, (float*)d_out, NP);
}